// Round 7
// baseline (254.782 us; speedup 1.0000x reference)
//
#include <hip/hip_runtime.h>

// y[rows[k]] += vals[k] * x[cols[k]]  — M=N=262144, NNZ=8388608, out 512x512 f32.
// 2-kernel pipeline (launch-boundary overhead ~15-25us each was the #2 cost):
//   hipMemsetAsync(cursors+done) -> counting-sort scatter into 32 row-bins (R3
//   structure, best measured) -> accum per (bin,slice) into 32KB LDS slab, dump
//   partials, last-done block per bin reduces slices into y (no reduce launch,
//   no grid barrier, no spinning).

#define BINS         32
#define ROW_SHIFT    13            // 8192 rows per bin
#define ROWS_PER_BIN 8192
#define ENT          4096          // entries per scatter block (16/thread)
#define CUR_STRIDE   32            // global counter padding: 1 per 128B line
#define SL           16            // accum slices per bin

typedef int   i32x4 __attribute__((ext_vector_type(4)));
typedef float f32x4 __attribute__((ext_vector_type(4)));

// ---------------- fallback path (known-correct) ----------------

__global__ __launch_bounds__(256) void zero_out_kernel(float* __restrict__ y, int n) {
    int i = blockIdx.x * blockDim.x + threadIdx.x;
    if (i < n) y[i] = 0.0f;
}

__global__ __launch_bounds__(256) void spmv_coo_scatter(
    const float* __restrict__ vals, const int* __restrict__ rows,
    const int* __restrict__ cols, const float* __restrict__ x,
    float* __restrict__ y, int nnz)
{
    int i = (blockIdx.x * blockDim.x + threadIdx.x) * 4;
    if (i + 3 < nnz) {
        float4 v = *reinterpret_cast<const float4*>(vals + i);
        int4   r = *reinterpret_cast<const int4*>(rows + i);
        int4   c = *reinterpret_cast<const int4*>(cols + i);
        atomicAdd(&y[r.x], v.x * x[c.x]);
        atomicAdd(&y[r.y], v.y * x[c.y]);
        atomicAdd(&y[r.z], v.z * x[c.z]);
        atomicAdd(&y[r.w], v.w * x[c.w]);
    } else {
        for (; i < nnz; ++i) atomicAdd(&y[rows[i]], vals[i] * x[cols[i]]);
    }
}

// ---------------- binned path ----------------

// Block-local counting sort + coalesced write of (key,contrib) into bin regions.
// R3 structure verbatim (72us best measured).
__global__ __launch_bounds__(256) void scatter2_kernel(
    const int*   __restrict__ rows, const int* __restrict__ cols,
    const float* __restrict__ vals, const float* __restrict__ x, int nnz,
    unsigned* __restrict__ gcur, unsigned cap,
    unsigned short* __restrict__ okeys, float* __restrict__ ocontrib)
{
    __shared__ unsigned cnt[BINS];
    __shared__ int      dstb[BINS];          // resv - lstart (signed index math)
    __shared__ unsigned cur2[BINS];
    __shared__ unsigned total_s;
    __shared__ unsigned short skey[ENT];
    __shared__ float          sval[ENT];
    __shared__ unsigned char  sbin[ENT];

    const int t = threadIdx.x;
    if (t < BINS) cnt[t] = 0u;
    __syncthreads();

    const int seg = blockIdx.x * ENT;

    int   rr[16];
    int   cc[16];
    float ff[16];

    // Pass A: load triplets. Keep all 16 col indices so the 16 x-gathers issue
    // as one independent batch (MLP), then multiply.
    if (seg + ENT <= nnz) {
        #pragma unroll
        for (int ch = 0; ch < 4; ++ch) {
            int base = seg + ch * 1024 + t * 4;
            i32x4 r4 = *reinterpret_cast<const i32x4*>(rows + base);
            i32x4 c4 = *reinterpret_cast<const i32x4*>(cols + base);
            f32x4 v4 = *reinterpret_cast<const f32x4*>(vals + base);
            rr[ch*4+0] = r4.x; cc[ch*4+0] = c4.x; ff[ch*4+0] = v4.x;
            rr[ch*4+1] = r4.y; cc[ch*4+1] = c4.y; ff[ch*4+1] = v4.y;
            rr[ch*4+2] = r4.z; cc[ch*4+2] = c4.z; ff[ch*4+2] = v4.z;
            rr[ch*4+3] = r4.w; cc[ch*4+3] = c4.w; ff[ch*4+3] = v4.w;
        }
        #pragma unroll
        for (int j = 0; j < 16; ++j) ff[j] *= x[cc[j]];
    } else {
        #pragma unroll
        for (int ch = 0; ch < 4; ++ch) {
            #pragma unroll
            for (int j = 0; j < 4; ++j) {
                int idx = seg + ch * 1024 + t * 4 + j;
                if (idx < nnz) { rr[ch*4+j] = rows[idx]; cc[ch*4+j] = cols[idx]; ff[ch*4+j] = vals[idx]; }
                else           { rr[ch*4+j] = -1; cc[ch*4+j] = 0; ff[ch*4+j] = 0.0f; }
            }
        }
        #pragma unroll
        for (int j = 0; j < 16; ++j) if (rr[j] >= 0) ff[j] *= x[cc[j]];
    }

    // Histogram (no-return LDS atomics).
    #pragma unroll
    for (int j = 0; j < 16; ++j)
        if (rr[j] >= 0) atomicAdd(&cnt[rr[j] >> ROW_SHIFT], 1u);
    __syncthreads();

    // Reserve global space per bin + shfl exclusive scan of local counts (wave 0).
    if (t < BINS) {
        unsigned c = cnt[t];
        unsigned resv = atomicAdd(&gcur[t * CUR_STRIDE], c);
        unsigned v = c;
        #pragma unroll
        for (int d = 1; d < BINS; d <<= 1) {
            unsigned o = __shfl_up(v, d, 64);
            if (t >= d) v += o;
        }
        unsigned ls = v - c;
        cur2[t] = ls;
        dstb[t] = (int)resv - (int)ls;
        if (t == BINS - 1) total_s = v;
    }
    __syncthreads();

    // Pass B: place entries grouped by bin in LDS.
    #pragma unroll
    for (int j = 0; j < 16; ++j) {
        if (rr[j] >= 0) {
            int b = rr[j] >> ROW_SHIFT;
            unsigned p = atomicAdd(&cur2[b], 1u);
            skey[p] = (unsigned short)(rr[j] & (ROWS_PER_BIN - 1));
            sval[p] = ff[j];
            sbin[p] = (unsigned char)b;
        }
    }
    __syncthreads();

    // Copy-out: contiguous in LDS == contiguous in the bin's global region.
    const unsigned total = total_s;
    for (unsigned i = t; i < total; i += 256) {
        int b = sbin[i];
        unsigned off = (unsigned)(dstb[b] + (int)i);   // position within bin region
        if (off < cap) {
            size_t dst = (size_t)b * cap + off;
            okeys[dst]    = skey[i];
            ocontrib[dst] = sval[i];
        }
    }
}

// One block per (bin, slice): accumulate slice entries into LDS acc, dump partial
// slab; the LAST slice block to finish a bin (device-scope done counter) reduces
// all SL slabs into y. No reduce launch; no grid-wide wait.
__global__ __launch_bounds__(512) void accum_fused_kernel(
    const unsigned short* __restrict__ okeys, const float* __restrict__ ocontrib,
    const unsigned* __restrict__ gcur, unsigned cap,
    float* __restrict__ partials, unsigned* __restrict__ donec,
    float* __restrict__ y)
{
    __shared__ float acc[ROWS_PER_BIN];
    __shared__ unsigned last_s;
    const int t   = threadIdx.x;
    const int bin = blockIdx.x / SL;
    const int sl  = blockIdx.x - bin * SL;

    float4 z = make_float4(0.f, 0.f, 0.f, 0.f);
    #pragma unroll
    for (int i = 0; i < ROWS_PER_BIN / (512 * 4); ++i)
        *reinterpret_cast<float4*>(&acc[(i * 512 + t) * 4]) = z;
    __syncthreads();

    unsigned count = gcur[bin * CUR_STRIDE];
    if (count > cap) count = cap;
    unsigned chunk = ((count + (unsigned)SL - 1u) / (unsigned)SL + 3u) & ~3u;
    unsigned lo = (unsigned)sl * chunk;
    unsigned hi = lo + chunk; if (hi > count) hi = count;

    const unsigned short* k = okeys    + (size_t)bin * cap;
    const float*          c = ocontrib + (size_t)bin * cap;

    unsigned i = lo + (unsigned)t * 4u;

    // 4x batch: 8 independent vector loads in flight before any LDS atomic.
    for (; i + 6147u < hi; i += 8192u) {
        ushort4 K[4];
        float4  C[4];
        #pragma unroll
        for (int j = 0; j < 4; ++j) K[j] = *reinterpret_cast<const ushort4*>(k + i + (unsigned)j * 2048u);
        #pragma unroll
        for (int j = 0; j < 4; ++j) C[j] = *reinterpret_cast<const float4*>(c + i + (unsigned)j * 2048u);
        #pragma unroll
        for (int j = 0; j < 4; ++j) {
            atomicAdd(&acc[K[j].x], C[j].x);
            atomicAdd(&acc[K[j].y], C[j].y);
            atomicAdd(&acc[K[j].z], C[j].z);
            atomicAdd(&acc[K[j].w], C[j].w);
        }
    }
    for (; i + 3u < hi; i += 2048u) {
        ushort4 k4 = *reinterpret_cast<const ushort4*>(k + i);
        float4  c4 = *reinterpret_cast<const float4*>(c + i);
        atomicAdd(&acc[k4.x], c4.x);
        atomicAdd(&acc[k4.y], c4.y);
        atomicAdd(&acc[k4.z], c4.z);
        atomicAdd(&acc[k4.w], c4.w);
    }
    for (; i < hi; ++i) atomicAdd(&acc[k[i]], c[i]);
    __syncthreads();

    // Dump partial slab (plain coalesced stores).
    float* p = partials + (size_t)blockIdx.x * ROWS_PER_BIN;
    #pragma unroll
    for (int i2 = 0; i2 < ROWS_PER_BIN / (512 * 4); ++i2) {
        int l = (i2 * 512 + t) * 4;
        *reinterpret_cast<float4*>(p + l) = *reinterpret_cast<const float4*>(&acc[l]);
    }

    // Last-done block reduces this bin. __syncthreads drains all waves' stores
    // (compiler emits vmcnt(0) before s_barrier); release fence + device-scope
    // RMW publishes; acquire fence on the winner orders its re-reads.
    __syncthreads();
    if (t == 0) {
        __threadfence();
        unsigned d = __hip_atomic_fetch_add(&donec[bin * CUR_STRIDE], 1u,
                                            __ATOMIC_ACQ_REL, __HIP_MEMORY_SCOPE_AGENT);
        last_s = (d == (unsigned)(SL - 1)) ? 1u : 0u;
    }
    __syncthreads();
    if (!last_s) return;
    __threadfence();

    const float* pb = partials + (size_t)bin * SL * ROWS_PER_BIN;
    float* yb = y + (size_t)bin * ROWS_PER_BIN;
    #pragma unroll
    for (int blk2 = 0; blk2 < ROWS_PER_BIN / (512 * 4); ++blk2) {
        int r0 = (blk2 * 512 + t) * 4;
        float4 s = make_float4(0.f, 0.f, 0.f, 0.f);
        #pragma unroll
        for (int j = 0; j < SL; ++j) {
            float4 v = *reinterpret_cast<const float4*>(pb + (size_t)j * ROWS_PER_BIN + r0);
            s.x += v.x; s.y += v.y; s.z += v.z; s.w += v.w;
        }
        *reinterpret_cast<float4*>(yb + r0) = s;
    }
}

extern "C" void kernel_launch(void* const* d_in, const int* in_sizes, int n_in,
                              void* d_out, int out_size, void* d_ws, size_t ws_size,
                              hipStream_t stream) {
    const float* x    = (const float*)d_in[0];
    const float* vals = (const float*)d_in[1];
    const int*   rows = (const int*)d_in[2];
    const int*   cols = (const int*)d_in[3];
    float* y = (float*)d_out;

    const int nnz  = in_sizes[1];
    const int bins = (out_size + ROWS_PER_BIN - 1) / ROWS_PER_BIN;

    unsigned cap = (unsigned)(nnz / (bins > 0 ? bins : 1)) + 16384u;   // ~32 sigma slack
    cap = (cap + 3u) & ~3u;

    auto align256 = [](size_t v) { return (v + 255) & ~(size_t)255; };

    size_t off_contrib  = 0;
    size_t off_keys     = align256(off_contrib + (size_t)BINS * cap * 4);
    size_t off_partials = align256(off_keys + (size_t)BINS * cap * 2);
    size_t off_gcur     = align256(off_partials + (size_t)BINS * SL * ROWS_PER_BIN * 4);
    size_t off_done     = off_gcur + (size_t)BINS * CUR_STRIDE * 4;
    size_t need         = align256(off_done + (size_t)BINS * CUR_STRIDE * 4);

    const bool ok = (bins == BINS) && (need <= ws_size) && (nnz > 0) &&
                    (out_size == BINS * ROWS_PER_BIN);

    if (!ok) {
        zero_out_kernel<<<(out_size + 255) / 256, 256, 0, stream>>>(y, out_size);
        spmv_coo_scatter<<<(nnz + 1023) / 1024, 256, 0, stream>>>(vals, rows, cols, x, y, nnz);
        return;
    }

    char* w = (char*)d_ws;
    float*          ocontrib = (float*)(w + off_contrib);
    unsigned short* okeys    = (unsigned short*)(w + off_keys);
    float*          partials = (float*)(w + off_partials);
    unsigned*       gcur     = (unsigned*)(w + off_gcur);
    unsigned*       donec    = (unsigned*)(w + off_done);

    // Zero cursors + done counters in one memset node (replaces init launch).
    hipMemsetAsync(gcur, 0, (size_t)2 * BINS * CUR_STRIDE * 4, stream);

    scatter2_kernel<<<(nnz + ENT - 1) / ENT, 256, 0, stream>>>(
        rows, cols, vals, x, nnz, gcur, cap, okeys, ocontrib);
    accum_fused_kernel<<<BINS * SL, 512, 0, stream>>>(
        okeys, ocontrib, gcur, cap, partials, donec, y);
}

// Round 8
// 220.753 us; speedup vs baseline: 1.1541x; 1.1541x over previous
//
#include <hip/hip_runtime.h>

// y[rows[k]] += vals[k] * x[cols[k]]  — M=N=262144, NNZ=8388608, out 512x512 f32.
// Pipeline: memset cursors -> counting-sort scatter into 32 row-bins -> per-
// (bin,slice) LDS accumulation -> slice reduction.
// R8: launch_bounds min-waves set on scatter/accum. Previous builds had VGPR=44/32
// (compiler targeting 8 waves/EU), which serialized every "MLP batch" — the real
// reason both kernels sat latency-bound at <25% of achievable BW.

#define BINS         32
#define ROW_SHIFT    13            // 8192 rows per bin
#define ROWS_PER_BIN 8192
#define ENT          4096          // entries per scatter block (16/thread)
#define CUR_STRIDE   32            // global cursor padding: 1 counter per 128B line
#define SL           16            // accum slices per bin

typedef int   i32x4 __attribute__((ext_vector_type(4)));
typedef float f32x4 __attribute__((ext_vector_type(4)));

// ---------------- fallback path (known-correct) ----------------

__global__ __launch_bounds__(256) void zero_out_kernel(float* __restrict__ y, int n) {
    int i = blockIdx.x * blockDim.x + threadIdx.x;
    if (i < n) y[i] = 0.0f;
}

__global__ __launch_bounds__(256) void spmv_coo_scatter(
    const float* __restrict__ vals, const int* __restrict__ rows,
    const int* __restrict__ cols, const float* __restrict__ x,
    float* __restrict__ y, int nnz)
{
    int i = (blockIdx.x * blockDim.x + threadIdx.x) * 4;
    if (i + 3 < nnz) {
        float4 v = *reinterpret_cast<const float4*>(vals + i);
        int4   r = *reinterpret_cast<const int4*>(rows + i);
        int4   c = *reinterpret_cast<const int4*>(cols + i);
        atomicAdd(&y[r.x], v.x * x[c.x]);
        atomicAdd(&y[r.y], v.y * x[c.y]);
        atomicAdd(&y[r.z], v.z * x[c.z]);
        atomicAdd(&y[r.w], v.w * x[c.w]);
    } else {
        for (; i < nnz; ++i) atomicAdd(&y[rows[i]], vals[i] * x[cols[i]]);
    }
}

// ---------------- binned path ----------------

// Block-local counting sort + coalesced write of (key,contrib) into bin regions.
// __launch_bounds__(256,4): 128-VGPR budget so the 16 x-gathers are genuinely
// in flight (44-VGPR builds serialized them). LDS caps blocks at 5/CU anyway.
__global__ __launch_bounds__(256, 4) void scatter2_kernel(
    const int*   __restrict__ rows, const int* __restrict__ cols,
    const float* __restrict__ vals, const float* __restrict__ x, int nnz,
    unsigned* __restrict__ gcur, unsigned cap,
    unsigned short* __restrict__ okeys, float* __restrict__ ocontrib)
{
    __shared__ unsigned cnt[BINS];
    __shared__ int      dstb[BINS];          // resv - lstart (signed index math)
    __shared__ unsigned cur2[BINS];
    __shared__ unsigned total_s;
    __shared__ unsigned short skey[ENT];
    __shared__ float          sval[ENT];
    __shared__ unsigned char  sbin[ENT];

    const int t = threadIdx.x;
    if (t < BINS) cnt[t] = 0u;
    __syncthreads();

    const int seg = blockIdx.x * ENT;

    int   rr[16];
    int   cc[16];
    float ff[16];

    // Pass A: load triplets; gather all 16 x[col] into xg[] as one independent
    // batch (now backed by enough VGPRs to actually stay in flight).
    if (seg + ENT <= nnz) {
        #pragma unroll
        for (int ch = 0; ch < 4; ++ch) {
            int base = seg + ch * 1024 + t * 4;
            i32x4 r4 = *reinterpret_cast<const i32x4*>(rows + base);
            i32x4 c4 = *reinterpret_cast<const i32x4*>(cols + base);
            f32x4 v4 = *reinterpret_cast<const f32x4*>(vals + base);
            rr[ch*4+0] = r4.x; cc[ch*4+0] = c4.x; ff[ch*4+0] = v4.x;
            rr[ch*4+1] = r4.y; cc[ch*4+1] = c4.y; ff[ch*4+1] = v4.y;
            rr[ch*4+2] = r4.z; cc[ch*4+2] = c4.z; ff[ch*4+2] = v4.z;
            rr[ch*4+3] = r4.w; cc[ch*4+3] = c4.w; ff[ch*4+3] = v4.w;
        }
        float xg[16];
        #pragma unroll
        for (int j = 0; j < 16; ++j) xg[j] = x[cc[j]];
        #pragma unroll
        for (int j = 0; j < 16; ++j) ff[j] *= xg[j];
    } else {
        #pragma unroll
        for (int ch = 0; ch < 4; ++ch) {
            #pragma unroll
            for (int j = 0; j < 4; ++j) {
                int idx = seg + ch * 1024 + t * 4 + j;
                if (idx < nnz) { rr[ch*4+j] = rows[idx]; cc[ch*4+j] = cols[idx]; ff[ch*4+j] = vals[idx]; }
                else           { rr[ch*4+j] = -1; cc[ch*4+j] = 0; ff[ch*4+j] = 0.0f; }
            }
        }
        #pragma unroll
        for (int j = 0; j < 16; ++j) if (rr[j] >= 0) ff[j] *= x[cc[j]];
    }

    // Histogram (no-return LDS atomics).
    #pragma unroll
    for (int j = 0; j < 16; ++j)
        if (rr[j] >= 0) atomicAdd(&cnt[rr[j] >> ROW_SHIFT], 1u);
    __syncthreads();

    // Reserve global space per bin + shfl exclusive scan of local counts (wave 0).
    if (t < BINS) {
        unsigned c = cnt[t];
        unsigned resv = atomicAdd(&gcur[t * CUR_STRIDE], c);
        unsigned v = c;
        #pragma unroll
        for (int d = 1; d < BINS; d <<= 1) {
            unsigned o = __shfl_up(v, d, 64);
            if (t >= d) v += o;
        }
        unsigned ls = v - c;
        cur2[t] = ls;
        dstb[t] = (int)resv - (int)ls;
        if (t == BINS - 1) total_s = v;
    }
    __syncthreads();

    // Pass B: place entries grouped by bin in LDS.
    #pragma unroll
    for (int j = 0; j < 16; ++j) {
        if (rr[j] >= 0) {
            int b = rr[j] >> ROW_SHIFT;
            unsigned p = atomicAdd(&cur2[b], 1u);
            skey[p] = (unsigned short)(rr[j] & (ROWS_PER_BIN - 1));
            sval[p] = ff[j];
            sbin[p] = (unsigned char)b;
        }
    }
    __syncthreads();

    // Copy-out: contiguous in LDS == contiguous in the bin's global region.
    const unsigned total = total_s;
    for (unsigned i = t; i < total; i += 256) {
        int b = sbin[i];
        unsigned off = (unsigned)(dstb[b] + (int)i);   // position within bin region
        if (off < cap) {
            size_t dst = (size_t)b * cap + off;
            okeys[dst]    = skey[i];
            ocontrib[dst] = sval[i];
        }
    }
}

// One block per (bin, slice): accumulate slice entries into LDS acc, dump partials.
// __launch_bounds__(512,4): 128-VGPR budget; 8x batch = 16 vector loads in flight
// per thread (32-VGPR builds serialized to ~2). Grid 512 = 2 blocks/CU regardless.
__global__ __launch_bounds__(512, 4) void accum2_kernel(
    const unsigned short* __restrict__ okeys, const float* __restrict__ ocontrib,
    const unsigned* __restrict__ gcur, unsigned cap,
    float* __restrict__ partials)
{
    __shared__ float acc[ROWS_PER_BIN];
    const int t   = threadIdx.x;
    const int bin = blockIdx.x / SL;
    const int sl  = blockIdx.x - bin * SL;

    float4 z = make_float4(0.f, 0.f, 0.f, 0.f);
    #pragma unroll
    for (int i = 0; i < ROWS_PER_BIN / (512 * 4); ++i)
        *reinterpret_cast<float4*>(&acc[(i * 512 + t) * 4]) = z;
    __syncthreads();

    unsigned count = gcur[bin * CUR_STRIDE];
    if (count > cap) count = cap;
    unsigned chunk = ((count + (unsigned)SL - 1u) / (unsigned)SL + 3u) & ~3u;
    unsigned lo = (unsigned)sl * chunk;
    unsigned hi = lo + chunk; if (hi > count) hi = count;

    const unsigned short* k = okeys    + (size_t)bin * cap;
    const float*          c = ocontrib + (size_t)bin * cap;

    unsigned i = lo + (unsigned)t * 4u;

    // 8x batch: 16 independent vector loads in flight before any LDS atomic.
    for (; i + 14339u < hi; i += 16384u) {
        ushort4 K[8];
        float4  C[8];
        #pragma unroll
        for (int j = 0; j < 8; ++j) K[j] = *reinterpret_cast<const ushort4*>(k + i + (unsigned)j * 2048u);
        #pragma unroll
        for (int j = 0; j < 8; ++j) C[j] = *reinterpret_cast<const float4*>(c + i + (unsigned)j * 2048u);
        #pragma unroll
        for (int j = 0; j < 8; ++j) {
            atomicAdd(&acc[K[j].x], C[j].x);
            atomicAdd(&acc[K[j].y], C[j].y);
            atomicAdd(&acc[K[j].z], C[j].z);
            atomicAdd(&acc[K[j].w], C[j].w);
        }
    }
    for (; i + 3u < hi; i += 2048u) {
        ushort4 k4 = *reinterpret_cast<const ushort4*>(k + i);
        float4  c4 = *reinterpret_cast<const float4*>(c + i);
        atomicAdd(&acc[k4.x], c4.x);
        atomicAdd(&acc[k4.y], c4.y);
        atomicAdd(&acc[k4.z], c4.z);
        atomicAdd(&acc[k4.w], c4.w);
    }
    for (; i < hi; ++i) atomicAdd(&acc[k[i]], c[i]);
    __syncthreads();

    float* p = partials + (size_t)blockIdx.x * ROWS_PER_BIN;
    #pragma unroll
    for (int i2 = 0; i2 < ROWS_PER_BIN / (512 * 4); ++i2) {
        int l = (i2 * 512 + t) * 4;
        *reinterpret_cast<float4*>(p + l) = *reinterpret_cast<const float4*>(&acc[l]);
    }
}

// Sum the SL partials per row, 4 rows per thread (float4).
__global__ __launch_bounds__(256) void reduce2_kernel(
    const float* __restrict__ partials, float* __restrict__ y, int out_size)
{
    int r0 = (blockIdx.x * 256 + threadIdx.x) * 4;
    if (r0 >= out_size) return;
    int bin = r0 >> ROW_SHIFT, local = r0 & (ROWS_PER_BIN - 1);
    const float* p = partials + ((size_t)bin * SL) * ROWS_PER_BIN + local;
    float4 s = make_float4(0.f, 0.f, 0.f, 0.f);
    #pragma unroll
    for (int j = 0; j < SL; ++j) {
        float4 v = *reinterpret_cast<const float4*>(p + (size_t)j * ROWS_PER_BIN);
        s.x += v.x; s.y += v.y; s.z += v.z; s.w += v.w;
    }
    *reinterpret_cast<float4*>(y + r0) = s;
}

extern "C" void kernel_launch(void* const* d_in, const int* in_sizes, int n_in,
                              void* d_out, int out_size, void* d_ws, size_t ws_size,
                              hipStream_t stream) {
    const float* x    = (const float*)d_in[0];
    const float* vals = (const float*)d_in[1];
    const int*   rows = (const int*)d_in[2];
    const int*   cols = (const int*)d_in[3];
    float* y = (float*)d_out;

    const int nnz  = in_sizes[1];
    const int bins = (out_size + ROWS_PER_BIN - 1) / ROWS_PER_BIN;

    unsigned cap = (unsigned)(nnz / (bins > 0 ? bins : 1)) + 16384u;   // ~32 sigma slack
    cap = (cap + 3u) & ~3u;

    auto align256 = [](size_t v) { return (v + 255) & ~(size_t)255; };

    size_t off_contrib  = 0;
    size_t off_keys     = align256(off_contrib + (size_t)BINS * cap * 4);
    size_t off_partials = align256(off_keys + (size_t)BINS * cap * 2);
    size_t off_gcur     = align256(off_partials + (size_t)BINS * SL * ROWS_PER_BIN * 4);
    size_t need         = align256(off_gcur + (size_t)BINS * CUR_STRIDE * 4);

    const bool ok = (bins == BINS) && (need <= ws_size) && (nnz > 0) &&
                    (out_size == BINS * ROWS_PER_BIN);

    if (!ok) {
        zero_out_kernel<<<(out_size + 255) / 256, 256, 0, stream>>>(y, out_size);
        spmv_coo_scatter<<<(nnz + 1023) / 1024, 256, 0, stream>>>(vals, rows, cols, x, y, nnz);
        return;
    }

    char* w = (char*)d_ws;
    float*          ocontrib = (float*)(w + off_contrib);
    unsigned short* okeys    = (unsigned short*)(w + off_keys);
    float*          partials = (float*)(w + off_partials);
    unsigned*       gcur     = (unsigned*)(w + off_gcur);

    // Zero cursors with a memset node (replaces the init launch).
    hipMemsetAsync(gcur, 0, (size_t)BINS * CUR_STRIDE * 4, stream);

    scatter2_kernel<<<(nnz + ENT - 1) / ENT, 256, 0, stream>>>(
        rows, cols, vals, x, nnz, gcur, cap, okeys, ocontrib);
    accum2_kernel<<<BINS * SL, 512, 0, stream>>>(okeys, ocontrib, gcur, cap, partials);
    reduce2_kernel<<<(out_size / 4 + 255) / 256, 256, 0, stream>>>(partials, y, out_size);
}